// Round 4
// baseline (363.934 us; speedup 1.0000x reference)
//
#include <hip/hip_runtime.h>
#include <math.h>

// MultiLocalCosineLinear: B=65536 rows, D=768, C=100, P=4950 pairs.
// out layout (all float32): [0..B)  = preds (class id as float)
//                           [B..3B) = logits, row-major (B,2)
//
// R3: pair-binned restructure. R0-R2 were latency-bound (~31% HBM) on the
// per-row random 6KB weight gather + per-row reduction chain. Now: bin rows
// by pair_idx, one block per pair keeps w0/w1 in registers (norms computed
// once per wave), streams its rows of x — the hot kernel has no gather on
// the critical path.

#define D_DIM 768
#define C_DIM 100
#define P_DIM 4950               // C*(C-1)/2
#define F4_ROW (D_DIM / 4)       // 192
#define EPS_N 1e-12

typedef float vf4 __attribute__((ext_vector_type(4)));

__device__ __forceinline__ bool vi_gt(float v0, int i0, float v1, int i1) {
    // lexicographic (value desc, index asc) — matches jax.lax.top_k + stable sort
    return (v0 > v1) || (v0 == v1 && i0 < i1);
}

#define DOT4D(acc, u, v) \
    acc += (double)u.x * v.x + (double)u.y * v.y + (double)u.z * v.z + (double)u.w * v.w
#define SQ4F(acc, u) \
    acc += u.x * u.x + u.y * u.y + u.z * u.z + u.w * u.w

// ---------- K_a: top-2 per row -> pair[r], histogram counts[p] ----------
__global__ __launch_bounds__(256) void top2_kernel(
    const float* __restrict__ first_out,
    int* __restrict__ pairbuf,
    int* __restrict__ counts,
    int B)
{
    const int lane = threadIdx.x & 63;
    const int r = (blockIdx.x << 2) + (threadIdx.x >> 6);
    if (r >= B) return;

    const float* fo = first_out + (size_t)r * C_DIM;
    float e0 = fo[lane];
    int   j1 = lane + 64;
    float e1 = (j1 < C_DIM) ? fo[j1] : -INFINITY;

    float v1, v2; int i1, i2;
    if (vi_gt(e1, j1, e0, lane)) { v1 = e1; i1 = j1;   v2 = e0; i2 = lane; }
    else                         { v1 = e0; i1 = lane; v2 = e1; i2 = j1; }

    #pragma unroll
    for (int m = 1; m < 64; m <<= 1) {
        float ov1 = __shfl_xor(v1, m, 64);
        int   oi1 = __shfl_xor(i1, m, 64);
        float ov2 = __shfl_xor(v2, m, 64);
        int   oi2 = __shfl_xor(i2, m, 64);
        if (vi_gt(ov1, oi1, v1, i1)) {
            float nv2; int ni2;
            if (vi_gt(v1, i1, ov2, oi2)) { nv2 = v1;  ni2 = i1; }
            else                         { nv2 = ov2; ni2 = oi2; }
            v1 = ov1; i1 = oi1; v2 = nv2; i2 = ni2;
        } else {
            if (vi_gt(ov1, oi1, v2, i2)) { v2 = ov1; i2 = oi1; }
        }
    }
    if (lane == 0) {
        const int a = min(i1, i2);
        const int b = max(i1, i2);
        const int p = b * (b - 1) / 2 + a;
        pairbuf[r] = p;
        atomicAdd(&counts[p], 1);
    }
}

// ---------- K_b: exclusive scan of counts[P] -> offsets[P] (single block) ----------
#define SCAN_T 256
#define CHUNK ((P_DIM + SCAN_T - 1) / SCAN_T)   // 20
__global__ __launch_bounds__(SCAN_T) void scan_kernel(
    const int* __restrict__ counts,
    int* __restrict__ offsets)
{
    __shared__ int sh[SCAN_T];
    const int t = threadIdx.x;
    int vals[CHUNK];
    int tot = 0;
    #pragma unroll
    for (int j = 0; j < CHUNK; ++j) {
        const int idx = t * CHUNK + j;
        const int v = (idx < P_DIM) ? counts[idx] : 0;
        vals[j] = v; tot += v;
    }
    sh[t] = tot;
    __syncthreads();
    for (int d = 1; d < SCAN_T; d <<= 1) {       // Hillis-Steele inclusive
        const int v = (t >= d) ? sh[t - d] : 0;
        __syncthreads();
        sh[t] += v;
        __syncthreads();
    }
    int run = (t == 0) ? 0 : sh[t - 1];          // exclusive prefix of this chunk
    #pragma unroll
    for (int j = 0; j < CHUNK; ++j) {
        const int idx = t * CHUNK + j;
        if (idx < P_DIM) offsets[idx] = run;
        run += vals[j];
    }
}

// ---------- K_c: scatter row ids into per-pair segments ----------
__global__ __launch_bounds__(256) void scatter_kernel(
    const int* __restrict__ pairbuf,
    const int* __restrict__ offsets,
    int* __restrict__ cursors,
    int* __restrict__ rowlist,
    int B)
{
    const int r = blockIdx.x * 256 + threadIdx.x;
    if (r >= B) return;
    const int p = pairbuf[r];
    const int pos = offsets[p] + atomicAdd(&cursors[p], 1);
    rowlist[pos] = r;
}

// ---------- K_d: one block per pair; weights in registers, stream rows ----------
__global__ __launch_bounds__(256) void pair_kernel(
    const float* __restrict__ x,
    const float* __restrict__ weights,
    const float* __restrict__ sigma,
    const int* __restrict__ counts,
    const int* __restrict__ offsets,
    const int* __restrict__ rowlist,
    float* __restrict__ out,
    int B)
{
    const int p = blockIdx.x;
    const int cnt = counts[p];
    if (cnt == 0) return;                        // uniform across block, no syncs used
    const int base = offsets[p];
    const int lane = threadIdx.x & 63;
    const int wave = threadIdx.x >> 6;

    // decode (a,b) from p: b = max index, a = p - b(b-1)/2
    int b = (int)floor((sqrt(8.0 * (double)p + 1.0) + 1.0) * 0.5);
    if (b * (b - 1) / 2 > p) --b;
    if ((b + 1) * b / 2 <= p) ++b;
    const int a = p - b * (b - 1) / 2;

    // load this pair's weights once into registers; norms via f64 butterfly
    const vf4* wv = (const vf4*)(weights + (size_t)p * (2 * D_DIM));
    vf4 w0[3], w1[3];
    double n0 = 0.0, n1 = 0.0;
    #pragma unroll
    for (int j = 0; j < 3; ++j) {
        w0[j] = wv[lane + j * 64];
        w1[j] = wv[F4_ROW + lane + j * 64];
        DOT4D(n0, w0[j], w0[j]);
        DOT4D(n1, w1[j], w1[j]);
    }
    #pragma unroll
    for (int m = 1; m < 64; m <<= 1) {
        n0 += __shfl_xor(n0, m, 64);
        n1 += __shfl_xor(n1, m, 64);
    }
    const double s    = (double)sigma[p];
    const double si0  = s / fmax(sqrt(n0), EPS_N);
    const double si1  = s / fmax(sqrt(n1), EPS_N);

    // stream this pair's rows: 2 rows per wave-iteration, 4 waves round-robin
    for (int i = wave * 2; i < cnt; i += 8) {
        const int r0 = rowlist[base + i];
        const bool has2 = (i + 1 < cnt);
        const int r1 = has2 ? rowlist[base + i + 1] : r0;

        const vf4* xa = (const vf4*)(x + (size_t)r0 * D_DIM);
        const vf4* xb = (const vf4*)(x + (size_t)r1 * D_DIM);

        float  xx0 = 0.f, xx1 = 0.f;
        double d00 = 0.0, d01 = 0.0, d10 = 0.0, d11 = 0.0;
        #pragma unroll
        for (int j = 0; j < 3; ++j) {
            const vf4 va = xa[lane + j * 64];
            const vf4 vb = xb[lane + j * 64];
            SQ4F(xx0, va);
            SQ4F(xx1, vb);
            DOT4D(d00, va, w0[j]);
            DOT4D(d01, va, w1[j]);
            DOT4D(d10, vb, w0[j]);
            DOT4D(d11, vb, w1[j]);
        }
        #pragma unroll
        for (int m = 1; m < 64; m <<= 1) {
            xx0 += __shfl_xor(xx0, m, 64);
            xx1 += __shfl_xor(xx1, m, 64);
            d00 += __shfl_xor(d00, m, 64);
            d01 += __shfl_xor(d01, m, 64);
            d10 += __shfl_xor(d10, m, 64);
            d11 += __shfl_xor(d11, m, 64);
        }

        if (lane == 0 || (lane == 1 && has2)) {
            const int    rr  = lane ? r1 : r0;
            const float  xxv = lane ? xx1 : xx0;
            const double dd0 = lane ? d10 : d00;
            const double dd1 = lane ? d11 : d01;
            const double inx = 1.0 / fmax(sqrt((double)xxv), EPS_N);
            const double l0  = si0 * dd0 * inx;
            const double l1  = si1 * dd1 * inx;
            const int sel = (l1 > l0) ? 1 : 0;   // jnp.argmax: first wins ties
            out[rr] = (float)(sel ? b : a);
            out[B + 2 * rr]     = (float)l0;
            out[B + 2 * rr + 1] = (float)l1;
        }
    }
}

extern "C" void kernel_launch(void* const* d_in, const int* in_sizes, int n_in,
                              void* d_out, int out_size, void* d_ws, size_t ws_size,
                              hipStream_t stream) {
    const float* x         = (const float*)d_in[0];
    const float* first_out = (const float*)d_in[1];
    const float* weights   = (const float*)d_in[2];
    const float* sigma     = (const float*)d_in[3];
    float* out = (float*)d_out;

    const int B = in_sizes[0] / D_DIM;   // 65536
    const int P = in_sizes[3];           // 4950

    // ws layout (ints): [counts P][cursors P][offsets P][pairbuf B][rowlist B]
    int* counts  = (int*)d_ws;
    int* cursors = counts + P;
    int* offsets = cursors + P;
    int* pairbuf = offsets + P;
    int* rowlist = pairbuf + B;

    hipMemsetAsync(counts, 0, 2 * (size_t)P * sizeof(int), stream);  // counts+cursors
    hipLaunchKernelGGL(top2_kernel, dim3((B + 3) / 4), dim3(256), 0, stream,
                       first_out, pairbuf, counts, B);
    hipLaunchKernelGGL(scan_kernel, dim3(1), dim3(SCAN_T), 0, stream,
                       counts, offsets);
    hipLaunchKernelGGL(scatter_kernel, dim3((B + 255) / 256), dim3(256), 0, stream,
                       pairbuf, offsets, cursors, rowlist, B);
    hipLaunchKernelGGL(pair_kernel, dim3(P), dim3(256), 0, stream,
                       x, weights, sigma, counts, offsets, rowlist, out, B);
}